// Round 2
// baseline (998.135 us; speedup 1.0000x reference)
//
#include <hip/hip_runtime.h>
#include <math.h>

// Problem constants (fixed by setup_inputs)
#define BATCH 8
#define CIN   256
#define COUT  256
#define HH    64
#define WW    64
#define KK    3
#define K2    9
#define CKTOT (CIN*K2)   // 2304
#define PB    32         // positions per block (half a row; same b, same y)
#define CCH   32         // channel chunk
#define CKL   (CCH*K2)   // 288 ck values per chunk
#define INV_STRIDE 0.125f

// ---------------- Kernel A: weight transpose [o][ck] -> wT[ck][o] ----------------
__global__ __launch_bounds__(256) void transpose_w(const float* __restrict__ w,
                                                   float* __restrict__ wT) {
    int e = blockIdx.x * 256 + threadIdx.x;   // e indexes wT linearly: e = ck*256 + o
    int o  = e & 255;
    int ck = e >> 8;
    wT[e] = w[o * CKTOT + ck];                // read uncoalesced (2.36MB, one-shot), write coalesced
}

// ---------------- Kernel B: fused offset + deform-conv + relu ----------------
__global__ __launch_bounds__(256) void align_conv(const float* __restrict__ x,
                                                  const float* __restrict__ anchors,
                                                  const float* __restrict__ wT,
                                                  float* __restrict__ out) {
    // meta: per (p,k): 4 clamped in-plane indices + 4 masked bilinear weights.
    // stride 5 padding -> lane stride 45 ints, gcd(45,32)=1 -> conflict-light.
    __shared__ int   midx[PB * K2][5];
    __shared__ float mw  [PB * K2][5];
    __shared__ float smp [CKL][PB];          // [ck_local][p], rows 128B

    const int tid = threadIdx.x;
    const int g0  = blockIdx.x * PB;         // first global position of block
    const int b   = g0 >> 12;                // 4096 positions per batch, 32 | 4096
    const float* __restrict__ xb = x + (size_t)b * CIN * HH * WW;

    // ---- phase 0: bilinear metadata for 32 positions x 9 kernel points ----
    for (int i = tid; i < PB * K2; i += 256) {
        int p = i / 9;
        int k = i - p * 9;
        int g = g0 + p;
        int l = g & 4095;
        const float* a = anchors + ((size_t)b * 4096 + l) * 5;
        float xc = a[0] * INV_STRIDE;
        float yc = a[1] * INV_STRIDE;
        float dw = (a[2] * INV_STRIDE) * (1.f / 3.f);
        float dh = (a[3] * INV_STRIDE) * (1.f / 3.f);
        float ang = a[4];
        float cs = cosf(ang);
        float sn = sinf(ang);
        float kxf = (float)(k % 3 - 1);
        float kyf = (float)(k / 3 - 1);
        float xk = dw * kxf;
        float yk = dh * kyf;
        float px = cs * xk - sn * yk + xc;   // absolute sample position
        float py = sn * xk + cs * yk + yc;

        float x0f = floorf(px), y0f = floorf(py);
        float wx1 = px - x0f,   wy1 = py - y0f;
        float wx0 = 1.f - wx1,  wy0 = 1.f - wy1;
        int x0 = (int)x0f, y0 = (int)y0f;
        int x1 = x0 + 1,   y1 = y0 + 1;

        bool vx0 = (x0 >= 0) & (x0 < WW);
        bool vx1 = (x1 >= 0) & (x1 < WW);
        bool vy0 = (y0 >= 0) & (y0 < HH);
        bool vy1 = (y1 >= 0) & (y1 < HH);
        int xc0 = min(max(x0, 0), WW - 1);
        int xc1 = min(max(x1, 0), WW - 1);
        int yc0 = min(max(y0, 0), HH - 1);
        int yc1 = min(max(y1, 0), HH - 1);

        midx[i][0] = yc0 * WW + xc0;  mw[i][0] = (vy0 & vx0) ? wy0 * wx0 : 0.f;
        midx[i][1] = yc0 * WW + xc1;  mw[i][1] = (vy0 & vx1) ? wy0 * wx1 : 0.f;
        midx[i][2] = yc1 * WW + xc0;  mw[i][2] = (vy1 & vx0) ? wy1 * wx0 : 0.f;
        midx[i][3] = yc1 * WW + xc1;  mw[i][3] = (vy1 & vx1) ? wy1 * wx1 : 0.f;
    }

    // register tile: thread owns outputs og*8..og*8+7  x  positions pg*4..pg*4+3
    const int og = tid & 31;
    const int pg = tid >> 5;
    float acc[8][4];
    #pragma unroll
    for (int oj = 0; oj < 8; ++oj)
        #pragma unroll
        for (int pj = 0; pj < 4; ++pj) acc[oj][pj] = 0.f;

    // ---- main loop over 8 channel chunks ----
    for (int cc = 0; cc < CIN / CCH; ++cc) {
        __syncthreads();   // meta ready (iter 0) / smp free (iter >0)

        // stage smp[ck_local][p]: 9216 samples, 36 per thread.
        // consecutive lanes -> consecutive p (same ck) -> gather rows are
        // mostly-contiguous x segments.
        #pragma unroll 4
        for (int r = 0; r < 36; ++r) {
            int j   = r * 256 + tid;     // 0..9215
            int ckl = j >> 5;            // 0..287
            int p   = j & 31;
            int cl  = ckl / 9;
            int kk  = ckl - cl * 9;
            int i   = p * 9 + kk;
            const float* xp = xb + (size_t)(cc * CCH + cl) * (HH * WW);
            float s = mw[i][0] * xp[midx[i][0]]
                    + mw[i][1] * xp[midx[i][1]]
                    + mw[i][2] * xp[midx[i][2]]
                    + mw[i][3] * xp[midx[i][3]];
            smp[ckl][p] = s;
        }
        __syncthreads();

        // contraction: per ck: 1 broadcast ds_read_b128 + 2 coalesced global
        // float4 (wT row, L1/L2-hit) + 32 FMA.
        const float* __restrict__ wrow = wT + ((size_t)cc * CKL) * COUT + og * 8;
        #pragma unroll 2
        for (int ckl = 0; ckl < CKL; ++ckl) {
            float4 s4 = *(const float4*)&smp[ckl][pg * 4];
            float4 w0 = *(const float4*)(wrow + (size_t)ckl * COUT);
            float4 w1 = *(const float4*)(wrow + (size_t)ckl * COUT + 4);
            const float ws[8] = {w0.x, w0.y, w0.z, w0.w, w1.x, w1.y, w1.z, w1.w};
            const float ss[4] = {s4.x, s4.y, s4.z, s4.w};
            #pragma unroll
            for (int oj = 0; oj < 8; ++oj)
                #pragma unroll
                for (int pj = 0; pj < 4; ++pj)
                    acc[oj][pj] += ss[pj] * ws[oj];
        }
    }

    // ---- epilogue: relu + store. positions pg*4..+3 are consecutive x. ----
    const int l0 = g0 & 4095;
    const int y  = l0 >> 6;
    const int x0 = (l0 & 63) + pg * 4;
    #pragma unroll
    for (int oj = 0; oj < 8; ++oj) {
        int o = og * 8 + oj;
        float4 v;
        v.x = fmaxf(acc[oj][0], 0.f);
        v.y = fmaxf(acc[oj][1], 0.f);
        v.z = fmaxf(acc[oj][2], 0.f);
        v.w = fmaxf(acc[oj][3], 0.f);
        *(float4*)&out[(((size_t)b * COUT + o) * HH + y) * WW + x0] = v;
    }
}

extern "C" void kernel_launch(void* const* d_in, const int* in_sizes, int n_in,
                              void* d_out, int out_size, void* d_ws, size_t ws_size,
                              hipStream_t stream) {
    const float* x       = (const float*)d_in[0];
    const float* anchors = (const float*)d_in[1];
    const float* w       = (const float*)d_in[2];
    float* wT  = (float*)d_ws;              // 2304*256*4 = 2.36 MB
    float* out = (float*)d_out;

    hipLaunchKernelGGL(transpose_w, dim3((CKTOT * COUT) / 256), dim3(256), 0, stream, w, wT);
    hipLaunchKernelGGL(align_conv, dim3((BATCH * HH * WW) / PB), dim3(256), 0, stream,
                       x, anchors, wT, out);
}

// Round 3
// 420.769 us; speedup vs baseline: 2.3722x; 2.3722x over previous
//
#include <hip/hip_runtime.h>
#include <math.h>

#define BATCH 8
#define CIN   256
#define COUT  256
#define HH    64
#define WW    64
#define K2    9
#define CKTOT (CIN*K2)       // 2304
#define PB    64             // positions per block = one output row (b,y)
#define CCH   32             // channels per chunk
#define NCH   (CIN/CCH)      // 8 chunks
#define ROWBLK 40            // 16B-blocks per smp row (36 used, padded so blk^7 stays in range; 160 dwords -> bank-invariant rows)
#define INV_STRIDE 0.125f

typedef __attribute__((ext_vector_type(8))) short bf16x8;
typedef __attribute__((ext_vector_type(4))) float f32x4;

union Pack16 { uint4 u; bf16x8 v; };

__device__ __forceinline__ unsigned bf16rne(float f) {
    union { float f; unsigned u; } a; a.f = f;
    return (a.u + 0x7FFFu + ((a.u >> 16) & 1u)) >> 16;   // round-to-nearest-even
}

// ---- Kernel A: w[o][c*9+kk] fp32 -> wbf[o][kk*256+c] bf16 (K reordered kk-major) ----
__global__ __launch_bounds__(256) void convert_w(const float* __restrict__ w,
                                                 ushort* __restrict__ wbf) {
    int e   = blockIdx.x * 256 + threadIdx.x;   // e = o*2304 + kk*256 + c
    int o   = e / CKTOT;
    int rem = e - o * CKTOT;
    int kk  = rem >> 8;
    int c   = rem & 255;
    wbf[e] = (ushort)bf16rne(w[o * CKTOT + c * K2 + kk]);
}

// ---- Kernel B: offset + bilinear gather (bf16) + MFMA contraction + relu ----
__global__ __launch_bounds__(512, 4) void align_conv(const float* __restrict__ x,
                                                     const float* __restrict__ anchors,
                                                     const ushort* __restrict__ wbf,
                                                     float* __restrict__ out) {
    __shared__ uint4  smp[PB * ROWBLK];          // 40 KB: [p][kk*4+cb blocks of 8 bf16], blk XOR (p&7)
    __shared__ ushort midx[PB * K2][4];          // 4.5 KB bilinear corner indices
    __shared__ float  mw  [PB * K2][5];          // 11.25 KB bilinear weights (stride 5: bank spread)

    const int tid = threadIdx.x;
    const int g0  = blockIdx.x * PB;
    const int b   = g0 >> 12;                    // 4096 positions per batch
    const int l0  = g0 & 4095;                   // multiple of 64 -> full row
    const int y   = l0 >> 6;
    const float* __restrict__ xb = x + (size_t)b * CIN * HH * WW;

    // ---- phase 0: bilinear metadata for 64 positions x 9 kernel points ----
    for (int i = tid; i < PB * K2; i += 512) {
        int p = i / 9;
        int k = i - p * 9;
        const float* a = anchors + ((size_t)b * 4096 + l0 + p) * 5;
        float xc = a[0] * INV_STRIDE;
        float yc = a[1] * INV_STRIDE;
        float dw = (a[2] * INV_STRIDE) * (1.f / 3.f);
        float dh = (a[3] * INV_STRIDE) * (1.f / 3.f);
        float ang = a[4];
        float cs = cosf(ang);
        float sn = sinf(ang);
        float kxf = (float)(k % 3 - 1);
        float kyf = (float)(k / 3 - 1);
        float xk = dw * kxf;
        float yk = dh * kyf;
        float px = cs * xk - sn * yk + xc;
        float py = sn * xk + cs * yk + yc;

        float x0f = floorf(px), y0f = floorf(py);
        float wx1 = px - x0f,   wy1 = py - y0f;
        float wx0 = 1.f - wx1,  wy0 = 1.f - wy1;
        int x0 = (int)x0f, y0 = (int)y0f;
        int x1 = x0 + 1,   y1 = y0 + 1;

        bool vx0 = (x0 >= 0) & (x0 < WW);
        bool vx1 = (x1 >= 0) & (x1 < WW);
        bool vy0 = (y0 >= 0) & (y0 < HH);
        bool vy1 = (y1 >= 0) & (y1 < HH);
        int xc0 = min(max(x0, 0), WW - 1);
        int xc1 = min(max(x1, 0), WW - 1);
        int yc0 = min(max(y0, 0), HH - 1);
        int yc1 = min(max(y1, 0), HH - 1);

        midx[i][0] = (ushort)(yc0 * WW + xc0);  mw[i][0] = (vy0 & vx0) ? wy0 * wx0 : 0.f;
        midx[i][1] = (ushort)(yc0 * WW + xc1);  mw[i][1] = (vy0 & vx1) ? wy0 * wx1 : 0.f;
        midx[i][2] = (ushort)(yc1 * WW + xc0);  mw[i][2] = (vy1 & vx0) ? wy1 * wx0 : 0.f;
        midx[i][3] = (ushort)(yc1 * WW + xc1);  mw[i][3] = (vy1 & vx1) ? wy1 * wx1 : 0.f;
    }

    const int lane = tid & 63;
    const int wid  = tid >> 6;       // 8 waves
    const int wm   = wid >> 2;       // 0/1: position half (32 rows)
    const int wn   = wid & 3;        // 0..3: output quarter (64 cols)
    const int lr   = lane & 15;
    const int kg   = lane >> 4;      // 0..3: K-subgroup

    f32x4 acc[2][4];
    #pragma unroll
    for (int mi = 0; mi < 2; ++mi)
        #pragma unroll
        for (int ni = 0; ni < 4; ++ni)
            acc[mi][ni] = (f32x4){0.f, 0.f, 0.f, 0.f};

    for (int ch = 0; ch < NCH; ++ch) {
        __syncthreads();   // meta ready (ch 0) / smp consumed (ch > 0)

        // ---- stage: 64p x 9kk x 32c samples -> bf16 in A-fragment order ----
        for (int t = tid; t < PB * K2 * (CCH / 8); t += 512) {   // 2304 tasks
            int p  = t & 63;
            int u  = t >> 6;          // 0..35
            int cb = u & 3;           // 8-channel sub-block
            int kk = u >> 2;          // 0..8
            int i  = p * 9 + kk;
            int i0 = midx[i][0], i1 = midx[i][1], i2 = midx[i][2], i3 = midx[i][3];
            float w0 = mw[i][0], w1 = mw[i][1], w2 = mw[i][2], w3 = mw[i][3];
            const float* xp = xb + (size_t)(ch * CCH + cb * 8) * (HH * WW);
            unsigned pk[4];
            #pragma unroll
            for (int j = 0; j < 4; ++j) {
                float s0 = w0 * xp[i0] + w1 * xp[i1] + w2 * xp[i2] + w3 * xp[i3];
                xp += HH * WW;
                float s1 = w0 * xp[i0] + w1 * xp[i1] + w2 * xp[i2] + w3 * xp[i3];
                xp += HH * WW;
                pk[j] = bf16rne(s0) | (bf16rne(s1) << 16);
            }
            int blk = kk * 4 + cb;
            smp[p * ROWBLK + (blk ^ (p & 7))] = make_uint4(pk[0], pk[1], pk[2], pk[3]);
        }
        __syncthreads();

        // ---- MFMA: 9 K-steps of 32 (one kk each) ----
        const ushort* wbase = wbf + (size_t)(wn * 64 + lr) * CKTOT + ch * CCH + kg * 8;
        const int p0 = wm * 32 + lr;
        #pragma unroll 2
        for (int kk = 0; kk < 9; ++kk) {
            int blk = kk * 4 + kg;
            Pack16 a0; a0.u = smp[p0 * ROWBLK + (blk ^ (p0 & 7))];
            Pack16 a1; a1.u = smp[(p0 + 16) * ROWBLK + (blk ^ (p0 & 7))];  // (p0+16)&7 == p0&7
            const ushort* wk = wbase + kk * 256;
            bf16x8 b0 = *(const bf16x8*)(wk);
            bf16x8 b1 = *(const bf16x8*)(wk + 16 * CKTOT);
            bf16x8 b2 = *(const bf16x8*)(wk + 32 * CKTOT);
            bf16x8 b3 = *(const bf16x8*)(wk + 48 * CKTOT);
            acc[0][0] = __builtin_amdgcn_mfma_f32_16x16x32_bf16(a0.v, b0, acc[0][0], 0, 0, 0);
            acc[0][1] = __builtin_amdgcn_mfma_f32_16x16x32_bf16(a0.v, b1, acc[0][1], 0, 0, 0);
            acc[0][2] = __builtin_amdgcn_mfma_f32_16x16x32_bf16(a0.v, b2, acc[0][2], 0, 0, 0);
            acc[0][3] = __builtin_amdgcn_mfma_f32_16x16x32_bf16(a0.v, b3, acc[0][3], 0, 0, 0);
            acc[1][0] = __builtin_amdgcn_mfma_f32_16x16x32_bf16(a1.v, b0, acc[1][0], 0, 0, 0);
            acc[1][1] = __builtin_amdgcn_mfma_f32_16x16x32_bf16(a1.v, b1, acc[1][1], 0, 0, 0);
            acc[1][2] = __builtin_amdgcn_mfma_f32_16x16x32_bf16(a1.v, b2, acc[1][2], 0, 0, 0);
            acc[1][3] = __builtin_amdgcn_mfma_f32_16x16x32_bf16(a1.v, b3, acc[1][3], 0, 0, 0);
        }
    }

    // ---- epilogue: relu + float4 stores (D: col=lane&15 -> o, row=(lane>>4)*4+reg -> p) ----
    #pragma unroll
    for (int mi = 0; mi < 2; ++mi) {
        int xo = wm * 32 + mi * 16 + kg * 4;
        #pragma unroll
        for (int ni = 0; ni < 4; ++ni) {
            int o = wn * 64 + ni * 16 + lr;
            float4 v;
            v.x = fmaxf(acc[mi][ni][0], 0.f);
            v.y = fmaxf(acc[mi][ni][1], 0.f);
            v.z = fmaxf(acc[mi][ni][2], 0.f);
            v.w = fmaxf(acc[mi][ni][3], 0.f);
            *(float4*)&out[(((size_t)b * COUT + o) * HH + y) * WW + xo] = v;
        }
    }
}

extern "C" void kernel_launch(void* const* d_in, const int* in_sizes, int n_in,
                              void* d_out, int out_size, void* d_ws, size_t ws_size,
                              hipStream_t stream) {
    const float* x       = (const float*)d_in[0];
    const float* anchors = (const float*)d_in[1];
    const float* w       = (const float*)d_in[2];
    ushort* wbf = (ushort*)d_ws;                 // 2304*256*2 = 1.18 MB
    float* out  = (float*)d_out;

    hipLaunchKernelGGL(convert_w, dim3((CKTOT * COUT) / 256), dim3(256), 0, stream, w, wbf);
    hipLaunchKernelGGL(align_conv, dim3((BATCH * HH * WW) / PB), dim3(512), 0, stream,
                       x, anchors, wbf, out);
}

// Round 4
// 269.097 us; speedup vs baseline: 3.7092x; 1.5636x over previous
//
#include <hip/hip_runtime.h>
#include <hip/hip_fp16.h>
#include <math.h>

#define BATCH 8
#define CIN   256
#define COUT  256
#define HH    64
#define WW    64
#define K2    9
#define CKTOT (CIN*K2)       // 2304
#define NPIX  (HH*WW)        // 4096
#define PB    64             // positions per block = one output row (b,y)
#define CCH   32             // channels per chunk
#define NCH   (CIN/CCH)      // 8 chunks
#define ROWBLK 40            // 16B-blocks per smp row (36 used + pad; 160 dwords -> bank-invariant rows, XOR fixes)
#define INV_STRIDE 0.125f

typedef __attribute__((ext_vector_type(8))) short bf16x8;
typedef __attribute__((ext_vector_type(4))) float f32x4;

union Pack16 { uint4 u; bf16x8 v; };

__device__ __forceinline__ unsigned bf16rne(float f) {
    union { float f; unsigned u; } a; a.f = f;
    return (a.u + 0x7FFFu + ((a.u >> 16) & 1u)) >> 16;   // round-to-nearest-even
}
__device__ __forceinline__ float bflo(unsigned u) {      // low bf16 -> f32
    union { unsigned u; float f; } a; a.u = u << 16; return a.f;
}
__device__ __forceinline__ float bfhi(unsigned u) {      // high bf16 -> f32
    union { unsigned u; float f; } a; a.u = u & 0xFFFF0000u; return a.f;
}

// ---- Kernel A: w[o][c*9+kk] fp32 -> wbf[o][kk*256+c] bf16 (K reordered kk-major) ----
__global__ __launch_bounds__(256) void convert_w(const float* __restrict__ w,
                                                 ushort* __restrict__ wbf) {
    int e   = blockIdx.x * 256 + threadIdx.x;   // e = o*2304 + kk*256 + c
    int o   = e / CKTOT;
    int rem = e - o * CKTOT;
    int kk  = rem >> 8;
    int c   = rem & 255;
    wbf[e] = (ushort)bf16rne(w[o * CKTOT + c * K2 + kk]);
}

// ---- Kernel T: x NCHW f32 -> xt NHWC bf16 (per-(b,y) 64x256 tile via LDS) ----
__global__ __launch_bounds__(256) void transpose_x(const float* __restrict__ x,
                                                   ushort* __restrict__ xt) {
    __shared__ ushort tile[WW][CIN + 2];        // +2: write-phase bank spread
    const int by = blockIdx.x;                   // b*64 + y
    const float* __restrict__ xp = x + (size_t)(by >> 6) * CIN * NPIX + (size_t)(by & 63) * WW;
    const int xx = threadIdx.x & 63;
    const int c4 = threadIdx.x >> 6;
    #pragma unroll 4
    for (int r = 0; r < 64; ++r) {               // c = r*4 + c4, lanes along xx: coalesced
        int c = r * 4 + c4;
        tile[xx][c] = (ushort)bf16rne(xp[(size_t)c * NPIX + xx]);
    }
    __syncthreads();
    ushort* __restrict__ op = xt + (size_t)by * WW * CIN;
    const int cc = threadIdx.x;                  // lanes along c: coalesced 512B rows
    #pragma unroll 4
    for (int r = 0; r < 64; ++r)
        op[(size_t)r * CIN + cc] = tile[r][cc];
}

// ---- Kernel B: offset + NHWC-bf16 bilinear gather + MFMA contraction + relu ----
__global__ __launch_bounds__(512, 6) void align_conv(const ushort* __restrict__ xt,
                                                     const float* __restrict__ anchors,
                                                     const ushort* __restrict__ wbf,
                                                     float* __restrict__ out) {
    __shared__ uint4   smp[PB * ROWBLK];         // 40 KB: [p][(kk*4+cb) ^ (p&7)] blocks of 8 bf16
    __shared__ ushort4 midx[PB * K2];            // 4.5 KB: 4 corner pixel indices
    __shared__ ushort4 mwh [PB * K2];            // 4.5 KB: 4 bilinear weights (f16)

    const int tid = threadIdx.x;
    const int g0  = blockIdx.x * PB;
    const int b   = g0 >> 12;
    const int l0  = g0 & 4095;
    const int y   = l0 >> 6;
    const ushort* __restrict__ xtb = xt + (size_t)b * NPIX * CIN;

    // ---- phase 0: bilinear metadata for 64 positions x 9 kernel points ----
    for (int i = tid; i < PB * K2; i += 512) {
        int p = i / 9;
        int k = i - p * 9;
        const float* a = anchors + ((size_t)b * 4096 + l0 + p) * 5;
        float xc = a[0] * INV_STRIDE;
        float yc = a[1] * INV_STRIDE;
        float dw = (a[2] * INV_STRIDE) * (1.f / 3.f);
        float dh = (a[3] * INV_STRIDE) * (1.f / 3.f);
        float ang = a[4];
        float cs = cosf(ang);
        float sn = sinf(ang);
        float kxf = (float)(k % 3 - 1);
        float kyf = (float)(k / 3 - 1);
        float xk = dw * kxf;
        float yk = dh * kyf;
        float px = cs * xk - sn * yk + xc;
        float py = sn * xk + cs * yk + yc;

        float x0f = floorf(px), y0f = floorf(py);
        float wx1 = px - x0f,   wy1 = py - y0f;
        float wx0 = 1.f - wx1,  wy0 = 1.f - wy1;
        int x0 = (int)x0f, y0 = (int)y0f;
        int x1 = x0 + 1,   y1 = y0 + 1;

        bool vx0 = (x0 >= 0) & (x0 < WW);
        bool vx1 = (x1 >= 0) & (x1 < WW);
        bool vy0 = (y0 >= 0) & (y0 < HH);
        bool vy1 = (y1 >= 0) & (y1 < HH);
        int xc0 = min(max(x0, 0), WW - 1);
        int xc1 = min(max(x1, 0), WW - 1);
        int yc0 = min(max(y0, 0), HH - 1);
        int yc1 = min(max(y1, 0), HH - 1);

        float f0 = (vy0 & vx0) ? wy0 * wx0 : 0.f;
        float f1 = (vy0 & vx1) ? wy0 * wx1 : 0.f;
        float f2 = (vy1 & vx0) ? wy1 * wx0 : 0.f;
        float f3 = (vy1 & vx1) ? wy1 * wx1 : 0.f;
        midx[i] = make_ushort4((ushort)(yc0 * WW + xc0), (ushort)(yc0 * WW + xc1),
                               (ushort)(yc1 * WW + xc0), (ushort)(yc1 * WW + xc1));
        mwh[i]  = make_ushort4(__half_as_ushort(__float2half(f0)),
                               __half_as_ushort(__float2half(f1)),
                               __half_as_ushort(__float2half(f2)),
                               __half_as_ushort(__float2half(f3)));
    }

    const int lane = tid & 63;
    const int wid  = tid >> 6;       // 8 waves
    const int wm   = wid >> 2;       // 0/1: position half (32 rows)
    const int wn   = wid & 3;        // 0..3: output quarter (64 cols)
    const int lr   = lane & 15;
    const int kg   = lane >> 4;      // 0..3: K-subgroup

    f32x4 acc[2][4];
    #pragma unroll
    for (int mi = 0; mi < 2; ++mi)
        #pragma unroll
        for (int ni = 0; ni < 4; ++ni)
            acc[mi][ni] = (f32x4){0.f, 0.f, 0.f, 0.f};

    for (int ch = 0; ch < NCH; ++ch) {
        __syncthreads();   // meta ready (ch 0) / smp consumed (ch > 0)

        // ---- stage: t = kk*256 + p*4 + cb -> 4 coalesced bf16x8 corner loads ----
        for (int t = tid; t < PB * K2 * 4; t += 512) {   // 2304 tasks
            int cb = t & 3;
            int pp = (t >> 2) & 63;
            int kk = t >> 8;
            int i  = pp * 9 + kk;
            ushort4 mi = midx[i];
            ushort4 mh = mwh[i];
            float w0 = __half2float(__ushort_as_half(mh.x));
            float w1 = __half2float(__ushort_as_half(mh.y));
            float w2 = __half2float(__ushort_as_half(mh.z));
            float w3 = __half2float(__ushort_as_half(mh.w));
            int ch0 = ch * CCH + cb * 8;
            uint4 c0 = *(const uint4*)(xtb + (size_t)mi.x * CIN + ch0);
            uint4 c1 = *(const uint4*)(xtb + (size_t)mi.y * CIN + ch0);
            uint4 c2 = *(const uint4*)(xtb + (size_t)mi.z * CIN + ch0);
            uint4 c3 = *(const uint4*)(xtb + (size_t)mi.w * CIN + ch0);
            uint pk[4];
            const uint u0[4] = {c0.x, c0.y, c0.z, c0.w};
            const uint u1[4] = {c1.x, c1.y, c1.z, c1.w};
            const uint u2[4] = {c2.x, c2.y, c2.z, c2.w};
            const uint u3[4] = {c3.x, c3.y, c3.z, c3.w};
            #pragma unroll
            for (int q = 0; q < 4; ++q) {
                float slo = w0 * bflo(u0[q]) + w1 * bflo(u1[q]) + w2 * bflo(u2[q]) + w3 * bflo(u3[q]);
                float shi = w0 * bfhi(u0[q]) + w1 * bfhi(u1[q]) + w2 * bfhi(u2[q]) + w3 * bfhi(u3[q]);
                pk[q] = bf16rne(slo) | (bf16rne(shi) << 16);
            }
            smp[pp * ROWBLK + ((kk * 4 + cb) ^ (pp & 7))] = make_uint4(pk[0], pk[1], pk[2], pk[3]);
        }
        __syncthreads();

        // ---- MFMA: 9 K-steps of 32 (one kk each) ----
        const ushort* wbase = wbf + (size_t)(wn * 64 + lr) * CKTOT + ch * CCH + kg * 8;
        const int p0 = wm * 32 + lr;
        #pragma unroll 2
        for (int kk = 0; kk < 9; ++kk) {
            int blk = kk * 4 + kg;
            Pack16 a0; a0.u = smp[p0 * ROWBLK + (blk ^ (p0 & 7))];
            Pack16 a1; a1.u = smp[(p0 + 16) * ROWBLK + (blk ^ (p0 & 7))];
            const ushort* wk = wbase + kk * 256;
            bf16x8 b0 = *(const bf16x8*)(wk);
            bf16x8 b1 = *(const bf16x8*)(wk + 16 * CKTOT);
            bf16x8 b2 = *(const bf16x8*)(wk + 32 * CKTOT);
            bf16x8 b3 = *(const bf16x8*)(wk + 48 * CKTOT);
            acc[0][0] = __builtin_amdgcn_mfma_f32_16x16x32_bf16(a0.v, b0, acc[0][0], 0, 0, 0);
            acc[0][1] = __builtin_amdgcn_mfma_f32_16x16x32_bf16(a0.v, b1, acc[0][1], 0, 0, 0);
            acc[0][2] = __builtin_amdgcn_mfma_f32_16x16x32_bf16(a0.v, b2, acc[0][2], 0, 0, 0);
            acc[0][3] = __builtin_amdgcn_mfma_f32_16x16x32_bf16(a0.v, b3, acc[0][3], 0, 0, 0);
            acc[1][0] = __builtin_amdgcn_mfma_f32_16x16x32_bf16(a1.v, b0, acc[1][0], 0, 0, 0);
            acc[1][1] = __builtin_amdgcn_mfma_f32_16x16x32_bf16(a1.v, b1, acc[1][1], 0, 0, 0);
            acc[1][2] = __builtin_amdgcn_mfma_f32_16x16x32_bf16(a1.v, b2, acc[1][2], 0, 0, 0);
            acc[1][3] = __builtin_amdgcn_mfma_f32_16x16x32_bf16(a1.v, b3, acc[1][3], 0, 0, 0);
        }
    }

    // ---- epilogue: relu + float4 stores (D: col=lane&15 -> o, row=(lane>>4)*4+reg -> p) ----
    #pragma unroll
    for (int mi = 0; mi < 2; ++mi) {
        int xo = wm * 32 + mi * 16 + kg * 4;
        #pragma unroll
        for (int ni = 0; ni < 4; ++ni) {
            int o = wn * 64 + ni * 16 + lr;
            float4 v;
            v.x = fmaxf(acc[mi][ni][0], 0.f);
            v.y = fmaxf(acc[mi][ni][1], 0.f);
            v.z = fmaxf(acc[mi][ni][2], 0.f);
            v.w = fmaxf(acc[mi][ni][3], 0.f);
            *(float4*)&out[(((size_t)b * COUT + o) * HH + y) * WW + xo] = v;
        }
    }
}

extern "C" void kernel_launch(void* const* d_in, const int* in_sizes, int n_in,
                              void* d_out, int out_size, void* d_ws, size_t ws_size,
                              hipStream_t stream) {
    const float* x       = (const float*)d_in[0];
    const float* anchors = (const float*)d_in[1];
    const float* w       = (const float*)d_in[2];
    ushort* xt  = (ushort*)d_ws;                              // 8*4096*256*2 = 16 MB
    ushort* wbf = (ushort*)((char*)d_ws + (size_t)BATCH * NPIX * CIN * 2); // 1.18 MB
    float* out  = (float*)d_out;

    hipLaunchKernelGGL(transpose_x, dim3(BATCH * HH), dim3(256), 0, stream, x, xt);
    hipLaunchKernelGGL(convert_w, dim3((CKTOT * COUT) / 256), dim3(256), 0, stream, w, wbf);
    hipLaunchKernelGGL(align_conv, dim3((BATCH * HH * WW) / PB), dim3(512), 0, stream,
                       xt, anchors, wbf, out);
}